// Round 8
// baseline (111.987 us; speedup 1.0000x reference)
//
#include <hip/hip_runtime.h>
#include <math.h>

#define BB 4
#define SS 1024
#define DM 768
#define HH 12
#define DEPTH 64
#define QBLK 8
#define PROWS 16
#define NROWS (BB * SS)   // 4096

typedef float vfloat4 __attribute__((ext_vector_type(4)));
typedef short bf16x8 __attribute__((ext_vector_type(8)));
typedef float f32x4 __attribute__((ext_vector_type(4)));

__device__ inline ushort f2bf(float x) {
    uint u = __float_as_uint(x);
    u += 0x7FFFu + ((u >> 16) & 1u);
    return (ushort)(u >> 16);
}

// ------- Kernel 1: projections. qh f32; kh bf16 row-major; vh bf16 TRANSPOSED -------
__global__ __launch_bounds__(256, 3) void proj_kernel(
    const float* __restrict__ q, const float* __restrict__ k, const float* __restrict__ v,
    const float* __restrict__ Wq, const float* __restrict__ bq,
    const float* __restrict__ Wk, const float* __restrict__ bk,
    const float* __restrict__ Wv, const float* __restrict__ bv,
    float* __restrict__ qh, ushort* __restrict__ khu, ushort* __restrict__ vhT)
{
    __shared__ __align__(16) float rows[PROWS][DM];      // 48 KB
    __shared__ float resT[DEPTH][PROWS + 1];             // 4.25 KB
    const int nrb  = NROWS / PROWS;                      // 256
    const int m    = blockIdx.x / nrb;
    const int rb   = blockIdx.x % nrb;
    const int row0 = rb * PROWS;
    const int t    = threadIdx.x;

    const float* src  = (m == 0) ? q  : (m == 1) ? k  : v;
    const float* W    = (m == 0) ? Wq : (m == 1) ? Wk : Wv;
    const float* bias = (m == 0) ? bq : (m == 1) ? bk : bv;

    const float4* s4 = (const float4*)(src + (size_t)row0 * DM);
    float4* r4 = (float4*)&rows[0][0];
    for (int i = t; i < PROWS * DM / 4; i += 256) r4[i] = s4[i];
    __syncthreads();

    const int d  = t & 63;
    const int rg = t >> 6;                               // 0..3 -> rows rg*4..rg*4+3
    const float* Wp = W + d;
    float a0 = bias[d], a1 = a0, a2 = a0, a3 = a0;
    #pragma unroll 8
    for (int i = 0; i < DM; i += 4) {
        const float wv0 = Wp[(size_t)(i + 0) * DEPTH];
        const float wv1 = Wp[(size_t)(i + 1) * DEPTH];
        const float wv2 = Wp[(size_t)(i + 2) * DEPTH];
        const float wv3 = Wp[(size_t)(i + 3) * DEPTH];
        const float4 r0 = *(const float4*)&rows[rg * 4 + 0][i];
        const float4 r1 = *(const float4*)&rows[rg * 4 + 1][i];
        const float4 r2 = *(const float4*)&rows[rg * 4 + 2][i];
        const float4 r3 = *(const float4*)&rows[rg * 4 + 3][i];
        a0 = fmaf(r0.x, wv0, a0); a0 = fmaf(r0.y, wv1, a0); a0 = fmaf(r0.z, wv2, a0); a0 = fmaf(r0.w, wv3, a0);
        a1 = fmaf(r1.x, wv0, a1); a1 = fmaf(r1.y, wv1, a1); a1 = fmaf(r1.z, wv2, a1); a1 = fmaf(r1.w, wv3, a1);
        a2 = fmaf(r2.x, wv0, a2); a2 = fmaf(r2.y, wv1, a2); a2 = fmaf(r2.z, wv2, a2); a2 = fmaf(r2.w, wv3, a2);
        a3 = fmaf(r3.x, wv0, a3); a3 = fmaf(r3.y, wv1, a3); a3 = fmaf(r3.z, wv2, a3); a3 = fmaf(r3.w, wv3, a3);
    }
    if (m == 2) {
        resT[d][rg * 4 + 0] = a0;
        resT[d][rg * 4 + 1] = a1;
        resT[d][rg * 4 + 2] = a2;
        resT[d][rg * 4 + 3] = a3;
        __syncthreads();
        #pragma unroll
        for (int e = t; e < DEPTH * PROWS; e += 256) {
            const int dd = e >> 4, rr = e & 15;
            vhT[(size_t)dd * NROWS + row0 + rr] = f2bf(resT[dd][rr]);
        }
    } else if (m == 1) {
        ushort* du = khu + (size_t)(row0 + rg * 4) * DEPTH + d;
        du[0] = f2bf(a0); du[DEPTH] = f2bf(a1); du[2 * DEPTH] = f2bf(a2); du[3 * DEPTH] = f2bf(a3);
    } else {
        float* dp = qh + (size_t)(row0 + rg * 4) * DEPTH + d;
        dp[0] = a0; dp[DEPTH] = a1; dp[2 * DEPTH] = a2; dp[3 * DEPTH] = a3;
    }
}

// ---------------- Kernel 2: Wc_red[d][j] = sum_h Wc[h*64+d][j] ----------------
__global__ __launch_bounds__(256) void wcred_kernel(
    const float* __restrict__ Wc, float* __restrict__ Wr)
{
    int idx = blockIdx.x * 256 + threadIdx.x;
    if (idx >= DEPTH * DM) return;
    int d = idx / DM, j = idx % DM;
    float s = 0.f;
    #pragma unroll
    for (int h = 0; h < HH; ++h)
        s += Wc[(size_t)(h * DEPTH + d) * DM + j];
    Wr[idx] = s;
}

// -------- Kernel 3: MFMA attention core — B-frags loaded DIRECTLY from global --------
__global__ __launch_bounds__(512, 4) void attn_core(
    const float* __restrict__ qh, const ushort* __restrict__ khu, const ushort* __restrict__ vhT,
    const float* __restrict__ Wr, const float* __restrict__ bc,
    float* __restrict__ out, float* __restrict__ attn)
{
    __shared__ __align__(16) ushort qf[16 * 72];         // Q bf16 (scaled), padded
    __shared__ __align__(16) ushort pf[16 * 1032];       // P bf16, padded
    __shared__ float redmax[16 * 8];
    __shared__ float redsum[16 * 8];
    __shared__ __align__(16) float part_f[8 * 256];      // PV partials
    __shared__ __align__(16) float ohT_f[64 * 12];       // transposed oh

    const int t = threadIdx.x, l = t & 63, wid = t >> 6;
    const int li = l & 15, g4 = l >> 4;
    const int blk = blockIdx.x, b = blk >> 7;
    const int q0 = (blk & 127) * QBLK;

    // init: qf rows 0-7 = bf16(qh*scale); qf rows 8-15 = 0; pf rows 8-15 = 0
    {
        const int qq = t >> 6, dd = t & 63;
        qf[qq * 72 + dd] = f2bf(qh[((size_t)b * SS + q0 + qq) * DEPTH + dd] * 0.28867513459481287f);
        for (int i = t; i < 8 * 72; i += 512) qf[8 * 72 + i] = 0;
        for (int i = t; i < 8 * 1032; i += 512) pf[8 * 1032 + i] = 0;
    }
    __syncthreads();

    // A-frags (Q): lane holds row=li, k = g4*8..+7 (+32 for chunk 1)
    const bf16x8 a0 = *(const bf16x8*)&qf[li * 72 + g4 * 8];
    const bf16x8 a1 = *(const bf16x8*)&qf[li * 72 + 32 + g4 * 8];

    f32x4 c[8];
    #pragma unroll
    for (int i = 0; i < 8; ++i) c[i] = (f32x4){0.f, 0.f, 0.f, 0.f};

    // ---- QK: B-frags straight from global (K is L2-resident). No LDS, no barriers ----
    const ushort* khb = khu + (size_t)b * SS * DEPTH;
    __builtin_amdgcn_s_setprio(1);
    #pragma unroll
    for (int s = 0; s < 4; ++s) {
        #pragma unroll
        for (int jj = 0; jj < 2; ++jj) {
            const int tile = s * 16 + wid + 8 * jj;      // keep c[ci] <-> column-tile map
            const int ci = 2 * s + jj;
            const ushort* kp = khb + (size_t)(tile * 16 + li) * DEPTH + g4 * 8;
            const bf16x8 b0 = *(const bf16x8*)kp;
            const bf16x8 b1 = *(const bf16x8*)(kp + 32);
            c[ci] = __builtin_amdgcn_mfma_f32_16x16x32_bf16(a0, b0, c[ci], 0, 0, 0);
            c[ci] = __builtin_amdgcn_mfma_f32_16x16x32_bf16(a1, b1, c[ci], 0, 0, 0);
        }
    }
    __builtin_amdgcn_s_setprio(0);

    // ---- softmax on C-frags: row = 4*g4+reg, col = tile*16+li ----
    float mx[4], sm[4], inv[4];
    #pragma unroll
    for (int r = 0; r < 4; ++r) {
        float m_ = c[0][r];
        #pragma unroll
        for (int i = 1; i < 8; ++i) m_ = fmaxf(m_, c[i][r]);
        #pragma unroll
        for (int off = 1; off < 16; off <<= 1) m_ = fmaxf(m_, __shfl_xor(m_, off));
        mx[r] = m_;
    }
    if (li == 0) {
        #pragma unroll
        for (int r = 0; r < 4; ++r) redmax[(4 * g4 + r) * 8 + wid] = mx[r];
    }
    __syncthreads();
    #pragma unroll
    for (int r = 0; r < 4; ++r) {
        float m_ = redmax[(4 * g4 + r) * 8];
        #pragma unroll
        for (int w2 = 1; w2 < 8; ++w2) m_ = fmaxf(m_, redmax[(4 * g4 + r) * 8 + w2]);
        mx[r] = m_;
        sm[r] = 0.f;
    }
    #pragma unroll
    for (int i = 0; i < 8; ++i) {
        #pragma unroll
        for (int r = 0; r < 4; ++r) {
            const float e = __expf(c[i][r] - mx[r]);
            c[i][r] = e;
            sm[r] += e;
        }
    }
    #pragma unroll
    for (int r = 0; r < 4; ++r) {
        float s_ = sm[r];
        #pragma unroll
        for (int off = 1; off < 16; off <<= 1) s_ += __shfl_xor(s_, off);
        sm[r] = s_;
    }
    if (li == 0) {
        #pragma unroll
        for (int r = 0; r < 4; ++r) redsum[(4 * g4 + r) * 8 + wid] = sm[r];
    }
    __syncthreads();
    #pragma unroll
    for (int r = 0; r < 4; ++r) {
        float s_ = 0.f;
        #pragma unroll
        for (int w2 = 0; w2 < 8; ++w2) s_ += redsum[(4 * g4 + r) * 8 + w2];
        inv[r] = 1.f / s_;
    }
    // write P (bf16) rows 0-7 to pf
    if (l < 32) {
        #pragma unroll
        for (int i = 0; i < 8; ++i) {
            const int colbase = (16 * (i >> 1) + wid + 8 * (i & 1)) * 16 + li;
            #pragma unroll
            for (int r = 0; r < 4; ++r)
                pf[(4 * g4 + r) * 1032 + colbase] = f2bf(c[i][r] * inv[r]);
        }
    }
    __syncthreads();

    // ---- PV: A from pf (LDS), B straight from vhT (global, L2-resident). No barriers ----
    const int dt = wid >> 1, par = wid & 1;
    const ushort* vtb = vhT + (size_t)b * SS;            // + d*NROWS + key
    f32x4 cp0 = {0.f, 0.f, 0.f, 0.f}, cp1 = {0.f, 0.f, 0.f, 0.f};
    __builtin_amdgcn_s_setprio(1);
    #pragma unroll
    for (int s = 0; s < 4; ++s) {
        #pragma unroll
        for (int c2 = 0; c2 < 4; ++c2) {
            const int cc = par + 2 * c2;
            const int kk = s * 256 + cc * 32 + g4 * 8;
            const bf16x8 ap = *(const bf16x8*)&pf[li * 1032 + kk];
            const bf16x8 bv = *(const bf16x8*)(vtb + (size_t)(dt * 16 + li) * NROWS + kk);
            if (s & 1) cp1 = __builtin_amdgcn_mfma_f32_16x16x32_bf16(ap, bv, cp1, 0, 0, 0);
            else       cp0 = __builtin_amdgcn_mfma_f32_16x16x32_bf16(ap, bv, cp0, 0, 0, 0);
        }
    }
    __builtin_amdgcn_s_setprio(0);
    const f32x4 cp = cp0 + cp1;

    // ---- reduce parity pairs -> ohT[64][12] ----
    #pragma unroll
    for (int r = 0; r < 4; ++r) part_f[wid * 256 + r * 64 + l] = cp[r];
    __syncthreads();
    {
        const int qq = t >> 6, dd = t & 63;
        const int ls = (qq >> 2) * 16 + (dd & 15), rr = qq & 3, w0 = (dd >> 4) * 2;
        ohT_f[dd * 12 + qq] = part_f[w0 * 256 + rr * 64 + ls] + part_f[(w0 + 1) * 256 + rr * 64 + ls];
    }
    __syncthreads();

    // ---- head-0 weight write from pf (drains under outGEMM) ----
    {
        const int qq = t >> 6, c0 = t & 63;
        float* a0p = attn + (((size_t)b * HH) * SS + (q0 + qq)) * SS;
        #pragma unroll
        for (int i = 0; i < 16; ++i) {
            const int col = c0 + 64 * i;
            const float val = __uint_as_float((uint)pf[qq * 1032 + col] << 16);
            __builtin_nontemporal_store(val, a0p + col);
        }
    }

    // ---- out rows = ohT @ Wr + bc ----
    for (int j = t; j < DM; j += 512) {
        float a[QBLK];
        const float bj = bc[j];
        #pragma unroll
        for (int r = 0; r < QBLK; ++r) a[r] = bj;
        const float* wc = Wr + j;
        #pragma unroll 16
        for (int d2 = 0; d2 < DEPTH; ++d2) {
            const float wv = wc[(size_t)d2 * DM];
            const float4 o0 = *(const float4*)&ohT_f[d2 * 12];
            const float4 o1 = *(const float4*)&ohT_f[d2 * 12 + 4];
            a[0] = fmaf(o0.x, wv, a[0]); a[1] = fmaf(o0.y, wv, a[1]);
            a[2] = fmaf(o0.z, wv, a[2]); a[3] = fmaf(o0.w, wv, a[3]);
            a[4] = fmaf(o1.x, wv, a[4]); a[5] = fmaf(o1.y, wv, a[5]);
            a[6] = fmaf(o1.z, wv, a[6]); a[7] = fmaf(o1.w, wv, a[7]);
        }
        float* ob = out + ((size_t)b * SS + q0) * DM + j;
        #pragma unroll
        for (int r = 0; r < QBLK; ++r)
            __builtin_nontemporal_store(a[r], ob + (size_t)r * DM);
    }
}

// ---------------- Kernel 4: broadcast head 0 -> heads 1..11 (pure streaming) ----------------
#define BROWS 2
__global__ __launch_bounds__(256) void bcast_kernel(float* __restrict__ attn)
{
    const int t = threadIdx.x;
    #pragma unroll
    for (int r = 0; r < BROWS; ++r) {
        const int gr = blockIdx.x * BROWS + r;           // 0 .. B*S-1
        const int b  = gr >> 10;
        const int qi = gr & (SS - 1);
        float* base = attn + (((size_t)b * HH) * SS + qi) * SS;
        const vfloat4 val = ((const vfloat4*)base)[t];   // head 0 row
        #pragma unroll
        for (int h = 1; h < HH; ++h)
            __builtin_nontemporal_store(val, (vfloat4*)(base + (size_t)h * SS * SS) + t);
    }
}

extern "C" void kernel_launch(void* const* d_in, const int* in_sizes, int n_in,
                              void* d_out, int out_size, void* d_ws, size_t ws_size,
                              hipStream_t stream) {
    const float* q  = (const float*)d_in[0];
    const float* k  = (const float*)d_in[1];
    const float* v  = (const float*)d_in[2];
    const float* Wq = (const float*)d_in[3];
    const float* bq = (const float*)d_in[4];
    const float* Wk = (const float*)d_in[5];
    const float* bk = (const float*)d_in[6];
    const float* Wv = (const float*)d_in[7];
    const float* bv = (const float*)d_in[8];
    const float* Wc = (const float*)d_in[9];
    const float* bc = (const float*)d_in[10];

    float* out  = (float*)d_out;                              // [B,S,DM]
    float* attn = out + (size_t)BB * SS * DM;                 // [B,H,S,S]

    float* ws = (float*)d_ws;
    const size_t NPROJ = (size_t)NROWS * DEPTH;               // 262144
    float* qh   = ws;                                         // f32
    ushort* khu = (ushort*)(ws + NPROJ);                      // bf16 row-major
    ushort* vhT = (ushort*)(ws + NPROJ + NPROJ / 2);          // bf16 transposed [DEPTH][NROWS]
    float* Wr   = ws + 2 * NPROJ;                             // 64*768 f32

    proj_kernel<<<3 * (NROWS / PROWS), 256, 0, stream>>>(q, k, v, Wq, bq, Wk, bk, Wv, bv, qh, khu, vhT);
    wcred_kernel<<<(DEPTH * DM + 255) / 256, 256, 0, stream>>>(Wc, Wr);
    attn_core<<<BB * (SS / QBLK), 512, 0, stream>>>(qh, khu, vhT, Wr, bc, out, attn);
    bcast_kernel<<<NROWS / BROWS, 256, 0, stream>>>(attn);
}

// Round 9
// 102.549 us; speedup vs baseline: 1.0920x; 1.0920x over previous
//
#include <hip/hip_runtime.h>
#include <math.h>

#define BB 4
#define SS 1024
#define DM 768
#define HH 12
#define DEPTH 64
#define QBLK 8
#define PROWS 16
#define NROWS (BB * SS)   // 4096

typedef float vfloat4 __attribute__((ext_vector_type(4)));
typedef short bf16x8 __attribute__((ext_vector_type(8)));
typedef float f32x4 __attribute__((ext_vector_type(4)));

__device__ inline ushort f2bf(float x) {
    uint u = __float_as_uint(x);
    u += 0x7FFFu + ((u >> 16) & 1u);
    return (ushort)(u >> 16);
}

// ---------------- Kernel 1: projections. qh f32; kh,vh bf16 row-major ----------------
__global__ __launch_bounds__(256, 3) void proj_kernel(
    const float* __restrict__ q, const float* __restrict__ k, const float* __restrict__ v,
    const float* __restrict__ Wq, const float* __restrict__ bq,
    const float* __restrict__ Wk, const float* __restrict__ bk,
    const float* __restrict__ Wv, const float* __restrict__ bv,
    float* __restrict__ qh, ushort* __restrict__ khu, ushort* __restrict__ vhu)
{
    __shared__ __align__(16) float rows[PROWS][DM];      // 48 KB
    const int nrb  = NROWS / PROWS;                      // 256
    const int m    = blockIdx.x / nrb;
    const int rb   = blockIdx.x % nrb;
    const int row0 = rb * PROWS;
    const int t    = threadIdx.x;

    const float* src  = (m == 0) ? q  : (m == 1) ? k  : v;
    const float* W    = (m == 0) ? Wq : (m == 1) ? Wk : Wv;
    const float* bias = (m == 0) ? bq : (m == 1) ? bk : bv;

    const float4* s4 = (const float4*)(src + (size_t)row0 * DM);
    float4* r4 = (float4*)&rows[0][0];
    for (int i = t; i < PROWS * DM / 4; i += 256) r4[i] = s4[i];
    __syncthreads();

    const int d  = t & 63;
    const int rg = t >> 6;                               // 0..3 -> rows rg*4..rg*4+3
    const float* Wp = W + d;
    float a0 = bias[d], a1 = a0, a2 = a0, a3 = a0;
    #pragma unroll 8
    for (int i = 0; i < DM; i += 4) {
        const float wv0 = Wp[(size_t)(i + 0) * DEPTH];
        const float wv1 = Wp[(size_t)(i + 1) * DEPTH];
        const float wv2 = Wp[(size_t)(i + 2) * DEPTH];
        const float wv3 = Wp[(size_t)(i + 3) * DEPTH];
        const float4 r0 = *(const float4*)&rows[rg * 4 + 0][i];
        const float4 r1 = *(const float4*)&rows[rg * 4 + 1][i];
        const float4 r2 = *(const float4*)&rows[rg * 4 + 2][i];
        const float4 r3 = *(const float4*)&rows[rg * 4 + 3][i];
        a0 = fmaf(r0.x, wv0, a0); a0 = fmaf(r0.y, wv1, a0); a0 = fmaf(r0.z, wv2, a0); a0 = fmaf(r0.w, wv3, a0);
        a1 = fmaf(r1.x, wv0, a1); a1 = fmaf(r1.y, wv1, a1); a1 = fmaf(r1.z, wv2, a1); a1 = fmaf(r1.w, wv3, a1);
        a2 = fmaf(r2.x, wv0, a2); a2 = fmaf(r2.y, wv1, a2); a2 = fmaf(r2.z, wv2, a2); a2 = fmaf(r2.w, wv3, a2);
        a3 = fmaf(r3.x, wv0, a3); a3 = fmaf(r3.y, wv1, a3); a3 = fmaf(r3.z, wv2, a3); a3 = fmaf(r3.w, wv3, a3);
    }
    const size_t base = (size_t)(row0 + rg * 4) * DEPTH + d;
    if (m == 0) {
        float* dp = qh + base;
        dp[0] = a0; dp[DEPTH] = a1; dp[2 * DEPTH] = a2; dp[3 * DEPTH] = a3;
    } else {
        ushort* du = ((m == 1) ? khu : vhu) + base;
        du[0] = f2bf(a0); du[DEPTH] = f2bf(a1); du[2 * DEPTH] = f2bf(a2); du[3 * DEPTH] = f2bf(a3);
    }
}

// ---------------- Kernel 2: Wc_red[d][j] = sum_h Wc[h*64+d][j] ----------------
__global__ __launch_bounds__(256) void wcred_kernel(
    const float* __restrict__ Wc, float* __restrict__ Wr)
{
    int idx = blockIdx.x * 256 + threadIdx.x;
    if (idx >= DEPTH * DM) return;
    int d = idx / DM, j = idx % DM;
    float s = 0.f;
    #pragma unroll
    for (int h = 0; h < HH; ++h)
        s += Wc[(size_t)(h * DEPTH + d) * DM + j];
    Wr[idx] = s;
}

// ------- Kernel 3: MFMA attention core; streams ALL 12 weight copies inline -------
__global__ __launch_bounds__(512, 4) void attn_core(
    const float* __restrict__ qh, const ushort* __restrict__ khu, const ushort* __restrict__ vhu,
    const float* __restrict__ Wr, const float* __restrict__ bc,
    float* __restrict__ out, float* __restrict__ attn)
{
    __shared__ __align__(16) ushort qf[16 * 72];         // Q bf16 (scaled), padded
    __shared__ __align__(16) ushort kvbuf[256 * 72];     // K stage / VT stage / part+ohT
    __shared__ __align__(16) ushort pf[16 * 1032];       // P bf16, padded
    __shared__ float redmax[16 * 8];
    __shared__ float redsum[16 * 8];

    const int t = threadIdx.x, l = t & 63, wid = t >> 6;
    const int li = l & 15, g4 = l >> 4;
    const int blk = blockIdx.x, b = blk >> 7;
    const int q0 = (blk & 127) * QBLK;
    const int key = t >> 1, hf = t & 1;                  // staging role: row key, 64B half hf

    // init: qf rows 0-7 = bf16(qh*scale); qf rows 8-15 = 0; pf rows 8-15 = 0
    {
        const int qq = t >> 6, dd = t & 63;
        qf[qq * 72 + dd] = f2bf(qh[((size_t)b * SS + q0 + qq) * DEPTH + dd] * 0.28867513459481287f);
        for (int i = t; i < 8 * 72; i += 512) qf[8 * 72 + i] = 0;
        for (int i = t; i < 8 * 1032; i += 512) pf[8 * 1032 + i] = 0;
    }

    const ushort* khb = khu + (size_t)b * SS * DEPTH;
    const ushort* vhb = vhu + (size_t)b * SS * DEPTH;

    // prefetch K stage 0 (coalesced: thread -> row key, 64B half hf)
    uint4 kr0, kr1, kr2, kr3;
    {
        const uint4* g = (const uint4*)(khb + (size_t)key * DEPTH + hf * 32);
        kr0 = g[0]; kr1 = g[1]; kr2 = g[2]; kr3 = g[3];
    }
    __syncthreads();

    // A-frags (Q): lane holds row=li, k = g4*8..+7 (+32 for chunk 1)
    const bf16x8 a0 = *(const bf16x8*)&qf[li * 72 + g4 * 8];
    const bf16x8 a1 = *(const bf16x8*)&qf[li * 72 + 32 + g4 * 8];

    f32x4 c[8];
    #pragma unroll
    for (int i = 0; i < 8; ++i) c[i] = (f32x4){0.f, 0.f, 0.f, 0.f};

    // ---- QK: 4 stages of 256 keys, double-buffered through registers ----
    #pragma unroll
    for (int s = 0; s < 4; ++s) {
        if (s) __syncthreads();                          // prev stage MFMAs done
        {
            uint4* d4 = (uint4*)&kvbuf[key * 72 + hf * 32];
            d4[0] = kr0; d4[1] = kr1; d4[2] = kr2; d4[3] = kr3;
        }
        if (s < 3) {                                     // issue next stage loads now
            const uint4* g = (const uint4*)(khb + (size_t)((s + 1) * 256 + key) * DEPTH + hf * 32);
            kr0 = g[0]; kr1 = g[1]; kr2 = g[2]; kr3 = g[3];
        }
        __syncthreads();
        __builtin_amdgcn_s_setprio(1);
        #pragma unroll
        for (int jj = 0; jj < 2; ++jj) {
            const int tl = wid + 8 * jj;
            const int ci = 2 * s + jj;
            const bf16x8 b0 = *(const bf16x8*)&kvbuf[(tl * 16 + li) * 72 + g4 * 8];
            const bf16x8 b1 = *(const bf16x8*)&kvbuf[(tl * 16 + li) * 72 + 32 + g4 * 8];
            c[ci] = __builtin_amdgcn_mfma_f32_16x16x32_bf16(a0, b0, c[ci], 0, 0, 0);
            c[ci] = __builtin_amdgcn_mfma_f32_16x16x32_bf16(a1, b1, c[ci], 0, 0, 0);
        }
        __builtin_amdgcn_s_setprio(0);
    }

    // prefetch V stage 0 (coalesced) -> latency hides under softmax
    bf16x8 vr0, vr1, vr2, vr3;
    {
        const bf16x8* g = (const bf16x8*)(vhb + (size_t)key * DEPTH + hf * 32);
        vr0 = g[0]; vr1 = g[1]; vr2 = g[2]; vr3 = g[3];
    }

    // ---- softmax on C-frags: row = 4*g4+reg, col = tile*16+li ----
    float mx[4], sm[4], inv[4];
    #pragma unroll
    for (int r = 0; r < 4; ++r) {
        float m_ = c[0][r];
        #pragma unroll
        for (int i = 1; i < 8; ++i) m_ = fmaxf(m_, c[i][r]);
        #pragma unroll
        for (int off = 1; off < 16; off <<= 1) m_ = fmaxf(m_, __shfl_xor(m_, off));
        mx[r] = m_;
    }
    if (li == 0) {
        #pragma unroll
        for (int r = 0; r < 4; ++r) redmax[(4 * g4 + r) * 8 + wid] = mx[r];
    }
    __syncthreads();
    #pragma unroll
    for (int r = 0; r < 4; ++r) {
        float m_ = redmax[(4 * g4 + r) * 8];
        #pragma unroll
        for (int w2 = 1; w2 < 8; ++w2) m_ = fmaxf(m_, redmax[(4 * g4 + r) * 8 + w2]);
        mx[r] = m_;
        sm[r] = 0.f;
    }
    #pragma unroll
    for (int i = 0; i < 8; ++i) {
        #pragma unroll
        for (int r = 0; r < 4; ++r) {
            const float e = __expf(c[i][r] - mx[r]);
            c[i][r] = e;
            sm[r] += e;
        }
    }
    #pragma unroll
    for (int r = 0; r < 4; ++r) {
        float s_ = sm[r];
        #pragma unroll
        for (int off = 1; off < 16; off <<= 1) s_ += __shfl_xor(s_, off);
        sm[r] = s_;
    }
    if (li == 0) {
        #pragma unroll
        for (int r = 0; r < 4; ++r) redsum[(4 * g4 + r) * 8 + wid] = sm[r];
    }
    __syncthreads();
    #pragma unroll
    for (int r = 0; r < 4; ++r) {
        float s_ = 0.f;
        #pragma unroll
        for (int w2 = 0; w2 < 8; ++w2) s_ += redsum[(4 * g4 + r) * 8 + w2];
        inv[r] = 1.f / s_;
    }
    // write P (bf16) rows 0-7 to pf
    if (l < 32) {
        #pragma unroll
        for (int i = 0; i < 8; ++i) {
            const int colbase = (16 * (i >> 1) + wid + 8 * (i & 1)) * 16 + li;
            #pragma unroll
            for (int r = 0; r < 4; ++r)
                pf[(4 * g4 + r) * 1032 + colbase] = f2bf(c[i][r] * inv[r]);
        }
    }
    __syncthreads();

    // ---- stream ALL 12 head-copies of the weight rows (fire-and-forget nt stores);
    //      drains underneath PV + reduce + outGEMM ----
    {
        const int qq = t >> 6, c0 = t & 63;
        const ushort* prow = &pf[qq * 1032];
        float* abase = attn + ((size_t)(b * HH) * SS + (q0 + qq)) * SS;
        #pragma unroll
        for (int i = 0; i < 4; ++i) {
            const int col = i * 256 + c0 * 4;
            vfloat4 v4;
            v4.x = __uint_as_float((uint)prow[col + 0] << 16);
            v4.y = __uint_as_float((uint)prow[col + 1] << 16);
            v4.z = __uint_as_float((uint)prow[col + 2] << 16);
            v4.w = __uint_as_float((uint)prow[col + 3] << 16);
            #pragma unroll
            for (int h = 0; h < HH; ++h)
                __builtin_nontemporal_store(v4, (vfloat4*)(abase + (size_t)h * SS * SS + col));
        }
    }

    // ---- PV: 4 stages of 256 k, double-buffered; coalesced V loads + LDS transpose ----
    f32x4 cp = {0.f, 0.f, 0.f, 0.f};
    const int dt = wid >> 1, par = wid & 1;
    ushort* VT = kvbuf;                                  // [64][264]
    #pragma unroll
    for (int s = 0; s < 4; ++s) {
        if (s) __syncthreads();                          // prev stage MFMAs done
        {
            #pragma unroll
            for (int i = 0; i < 8; ++i) {
                VT[(hf * 32 + i     ) * 264 + key] = (ushort)vr0[i];
                VT[(hf * 32 + 8 + i ) * 264 + key] = (ushort)vr1[i];
                VT[(hf * 32 + 16 + i) * 264 + key] = (ushort)vr2[i];
                VT[(hf * 32 + 24 + i) * 264 + key] = (ushort)vr3[i];
            }
        }
        if (s < 3) {                                     // issue next stage loads now
            const bf16x8* g = (const bf16x8*)(vhb + (size_t)((s + 1) * 256 + key) * DEPTH + hf * 32);
            vr0 = g[0]; vr1 = g[1]; vr2 = g[2]; vr3 = g[3];
        }
        __syncthreads();
        __builtin_amdgcn_s_setprio(1);
        #pragma unroll
        for (int c2 = 0; c2 < 4; ++c2) {
            const int cc = par + 2 * c2;
            const bf16x8 ap = *(const bf16x8*)&pf[li * 1032 + s * 256 + cc * 32 + g4 * 8];
            const bf16x8 bv = *(const bf16x8*)&VT[(dt * 16 + li) * 264 + cc * 32 + g4 * 8];
            cp = __builtin_amdgcn_mfma_f32_16x16x32_bf16(ap, bv, cp, 0, 0, 0);
        }
        __builtin_amdgcn_s_setprio(0);
    }
    __syncthreads();

    // ---- reduce parity pairs -> ohT[64][12] ----
    float* part_f = (float*)kvbuf;                       // [8][256]
    float* ohT_f  = ((float*)kvbuf) + 2048;              // [64][12]
    #pragma unroll
    for (int r = 0; r < 4; ++r) part_f[wid * 256 + r * 64 + l] = cp[r];
    __syncthreads();
    {
        const int qq = t >> 6, dd = t & 63;
        const int ls = (qq >> 2) * 16 + (dd & 15), rr = qq & 3, w0 = (dd >> 4) * 2;
        ohT_f[dd * 12 + qq] = part_f[w0 * 256 + rr * 64 + ls] + part_f[(w0 + 1) * 256 + rr * 64 + ls];
    }
    __syncthreads();

    // ---- out rows = ohT @ Wr + bc ----
    for (int j = t; j < DM; j += 512) {
        float a[QBLK];
        const float bj = bc[j];
        #pragma unroll
        for (int r = 0; r < QBLK; ++r) a[r] = bj;
        const float* wc = Wr + j;
        #pragma unroll 16
        for (int d2 = 0; d2 < DEPTH; ++d2) {
            const float wv = wc[(size_t)d2 * DM];
            const float4 o0 = *(const float4*)&ohT_f[d2 * 12];
            const float4 o1 = *(const float4*)&ohT_f[d2 * 12 + 4];
            a[0] = fmaf(o0.x, wv, a[0]); a[1] = fmaf(o0.y, wv, a[1]);
            a[2] = fmaf(o0.z, wv, a[2]); a[3] = fmaf(o0.w, wv, a[3]);
            a[4] = fmaf(o1.x, wv, a[4]); a[5] = fmaf(o1.y, wv, a[5]);
            a[6] = fmaf(o1.z, wv, a[6]); a[7] = fmaf(o1.w, wv, a[7]);
        }
        float* ob = out + ((size_t)b * SS + q0) * DM + j;
        #pragma unroll
        for (int r = 0; r < QBLK; ++r)
            __builtin_nontemporal_store(a[r], ob + (size_t)r * DM);
    }
}

extern "C" void kernel_launch(void* const* d_in, const int* in_sizes, int n_in,
                              void* d_out, int out_size, void* d_ws, size_t ws_size,
                              hipStream_t stream) {
    const float* q  = (const float*)d_in[0];
    const float* k  = (const float*)d_in[1];
    const float* v  = (const float*)d_in[2];
    const float* Wq = (const float*)d_in[3];
    const float* bq = (const float*)d_in[4];
    const float* Wk = (const float*)d_in[5];
    const float* bk = (const float*)d_in[6];
    const float* Wv = (const float*)d_in[7];
    const float* bv = (const float*)d_in[8];
    const float* Wc = (const float*)d_in[9];
    const float* bc = (const float*)d_in[10];

    float* out  = (float*)d_out;                              // [B,S,DM]
    float* attn = out + (size_t)BB * SS * DM;                 // [B,H,S,S]

    float* ws = (float*)d_ws;
    const size_t NPROJ = (size_t)NROWS * DEPTH;               // 262144
    float* qh   = ws;                                         // f32
    ushort* khu = (ushort*)(ws + NPROJ);                      // bf16
    ushort* vhu = (ushort*)(ws + NPROJ + NPROJ / 2);          // bf16
    float* Wr   = ws + 2 * NPROJ;                             // 64*768 f32

    wcred_kernel<<<(DEPTH * DM + 255) / 256, 256, 0, stream>>>(Wc, Wr);
    proj_kernel<<<3 * (NROWS / PROWS), 256, 0, stream>>>(q, k, v, Wq, bq, Wk, bk, Wv, bv, qh, khu, vhu);
    attn_core<<<BB * (SS / QBLK), 512, 0, stream>>>(qh, khu, vhu, Wr, bc, out, attn);
}

// Round 10
// 100.086 us; speedup vs baseline: 1.1189x; 1.0246x over previous
//
#include <hip/hip_runtime.h>
#include <math.h>

#define BB 4
#define SS 1024
#define DM 768
#define HH 12
#define DEPTH 64
#define QBLK 8
#define PROWS 16
#define NROWS (BB * SS)   // 4096

typedef float vfloat4 __attribute__((ext_vector_type(4)));
typedef short bf16x8 __attribute__((ext_vector_type(8)));
typedef float f32x4 __attribute__((ext_vector_type(4)));

__device__ inline ushort f2bf(float x) {
    uint u = __float_as_uint(x);
    u += 0x7FFFu + ((u >> 16) & 1u);
    return (ushort)(u >> 16);
}

// ---------------- Kernel 1: projections. qh f32; kh,vh bf16 row-major ----------------
__global__ __launch_bounds__(256, 3) void proj_kernel(
    const float* __restrict__ q, const float* __restrict__ k, const float* __restrict__ v,
    const float* __restrict__ Wq, const float* __restrict__ bq,
    const float* __restrict__ Wk, const float* __restrict__ bk,
    const float* __restrict__ Wv, const float* __restrict__ bv,
    float* __restrict__ qh, ushort* __restrict__ khu, ushort* __restrict__ vhu)
{
    __shared__ __align__(16) float rows[PROWS][DM];      // 48 KB
    const int nrb  = NROWS / PROWS;                      // 256
    const int m    = blockIdx.x / nrb;
    const int rb   = blockIdx.x % nrb;
    const int row0 = rb * PROWS;
    const int t    = threadIdx.x;

    const float* src  = (m == 0) ? q  : (m == 1) ? k  : v;
    const float* W    = (m == 0) ? Wq : (m == 1) ? Wk : Wv;
    const float* bias = (m == 0) ? bq : (m == 1) ? bk : bv;

    const float4* s4 = (const float4*)(src + (size_t)row0 * DM);
    float4* r4 = (float4*)&rows[0][0];
    for (int i = t; i < PROWS * DM / 4; i += 256) r4[i] = s4[i];
    __syncthreads();

    const int d  = t & 63;
    const int rg = t >> 6;                               // 0..3 -> rows rg*4..rg*4+3
    const float* Wp = W + d;
    float a0 = bias[d], a1 = a0, a2 = a0, a3 = a0;
    #pragma unroll 8
    for (int i = 0; i < DM; i += 4) {
        const float wv0 = Wp[(size_t)(i + 0) * DEPTH];
        const float wv1 = Wp[(size_t)(i + 1) * DEPTH];
        const float wv2 = Wp[(size_t)(i + 2) * DEPTH];
        const float wv3 = Wp[(size_t)(i + 3) * DEPTH];
        const float4 r0 = *(const float4*)&rows[rg * 4 + 0][i];
        const float4 r1 = *(const float4*)&rows[rg * 4 + 1][i];
        const float4 r2 = *(const float4*)&rows[rg * 4 + 2][i];
        const float4 r3 = *(const float4*)&rows[rg * 4 + 3][i];
        a0 = fmaf(r0.x, wv0, a0); a0 = fmaf(r0.y, wv1, a0); a0 = fmaf(r0.z, wv2, a0); a0 = fmaf(r0.w, wv3, a0);
        a1 = fmaf(r1.x, wv0, a1); a1 = fmaf(r1.y, wv1, a1); a1 = fmaf(r1.z, wv2, a1); a1 = fmaf(r1.w, wv3, a1);
        a2 = fmaf(r2.x, wv0, a2); a2 = fmaf(r2.y, wv1, a2); a2 = fmaf(r2.z, wv2, a2); a2 = fmaf(r2.w, wv3, a2);
        a3 = fmaf(r3.x, wv0, a3); a3 = fmaf(r3.y, wv1, a3); a3 = fmaf(r3.z, wv2, a3); a3 = fmaf(r3.w, wv3, a3);
    }
    const size_t base = (size_t)(row0 + rg * 4) * DEPTH + d;
    if (m == 0) {
        float* dp = qh + base;
        dp[0] = a0; dp[DEPTH] = a1; dp[2 * DEPTH] = a2; dp[3 * DEPTH] = a3;
    } else {
        ushort* du = ((m == 1) ? khu : vhu) + base;
        du[0] = f2bf(a0); du[DEPTH] = f2bf(a1); du[2 * DEPTH] = f2bf(a2); du[3 * DEPTH] = f2bf(a3);
    }
}

// ---------------- Kernel 2: Wc_red[d][j] = sum_h Wc[h*64+d][j] ----------------
__global__ __launch_bounds__(256) void wcred_kernel(
    const float* __restrict__ Wc, float* __restrict__ Wr)
{
    int idx = blockIdx.x * 256 + threadIdx.x;
    if (idx >= DEPTH * DM) return;
    int d = idx / DM, j = idx % DM;
    float s = 0.f;
    #pragma unroll
    for (int h = 0; h < HH; ++h)
        s += Wc[(size_t)(h * DEPTH + d) * DM + j];
    Wr[idx] = s;
}

// ------- Kernel 3: MFMA attention core; 12-head weight burst at the VERY END -------
__global__ __launch_bounds__(512, 4) void attn_core(
    const float* __restrict__ qh, const ushort* __restrict__ khu, const ushort* __restrict__ vhu,
    const float* __restrict__ Wr, const float* __restrict__ bc,
    float* __restrict__ out, float* __restrict__ attn)
{
    __shared__ __align__(16) ushort qf[16 * 72];         // Q bf16 (scaled), padded
    __shared__ __align__(16) ushort kvbuf[256 * 72];     // K stage / VT stage / part+ohT
    __shared__ __align__(16) ushort pf[16 * 1032];       // P bf16, padded
    __shared__ float redmax[16 * 8];
    __shared__ float redsum[16 * 8];

    const int t = threadIdx.x, l = t & 63, wid = t >> 6;
    const int li = l & 15, g4 = l >> 4;
    const int blk = blockIdx.x, b = blk >> 7;
    const int q0 = (blk & 127) * QBLK;
    const int key = t >> 1, hf = t & 1;                  // staging role: row key, 64B half hf

    // init: qf rows 0-7 = bf16(qh*scale); qf rows 8-15 = 0; pf rows 8-15 = 0
    {
        const int qq = t >> 6, dd = t & 63;
        qf[qq * 72 + dd] = f2bf(qh[((size_t)b * SS + q0 + qq) * DEPTH + dd] * 0.28867513459481287f);
        for (int i = t; i < 8 * 72; i += 512) qf[8 * 72 + i] = 0;
        for (int i = t; i < 8 * 1032; i += 512) pf[8 * 1032 + i] = 0;
    }

    const ushort* khb = khu + (size_t)b * SS * DEPTH;
    const ushort* vhb = vhu + (size_t)b * SS * DEPTH;

    // prefetch K stage 0 (coalesced: thread -> row key, 64B half hf)
    uint4 kr0, kr1, kr2, kr3;
    {
        const uint4* g = (const uint4*)(khb + (size_t)key * DEPTH + hf * 32);
        kr0 = g[0]; kr1 = g[1]; kr2 = g[2]; kr3 = g[3];
    }
    __syncthreads();

    // A-frags (Q): lane holds row=li, k = g4*8..+7 (+32 for chunk 1)
    const bf16x8 a0 = *(const bf16x8*)&qf[li * 72 + g4 * 8];
    const bf16x8 a1 = *(const bf16x8*)&qf[li * 72 + 32 + g4 * 8];

    f32x4 c[8];
    #pragma unroll
    for (int i = 0; i < 8; ++i) c[i] = (f32x4){0.f, 0.f, 0.f, 0.f};

    // ---- QK: 4 stages of 256 keys, double-buffered through registers ----
    #pragma unroll
    for (int s = 0; s < 4; ++s) {
        if (s) __syncthreads();                          // prev stage MFMAs done
        {
            uint4* d4 = (uint4*)&kvbuf[key * 72 + hf * 32];
            d4[0] = kr0; d4[1] = kr1; d4[2] = kr2; d4[3] = kr3;
        }
        if (s < 3) {                                     // issue next stage loads now
            const uint4* g = (const uint4*)(khb + (size_t)((s + 1) * 256 + key) * DEPTH + hf * 32);
            kr0 = g[0]; kr1 = g[1]; kr2 = g[2]; kr3 = g[3];
        }
        __syncthreads();
        __builtin_amdgcn_s_setprio(1);
        #pragma unroll
        for (int jj = 0; jj < 2; ++jj) {
            const int tl = wid + 8 * jj;
            const int ci = 2 * s + jj;
            const bf16x8 b0 = *(const bf16x8*)&kvbuf[(tl * 16 + li) * 72 + g4 * 8];
            const bf16x8 b1 = *(const bf16x8*)&kvbuf[(tl * 16 + li) * 72 + 32 + g4 * 8];
            c[ci] = __builtin_amdgcn_mfma_f32_16x16x32_bf16(a0, b0, c[ci], 0, 0, 0);
            c[ci] = __builtin_amdgcn_mfma_f32_16x16x32_bf16(a1, b1, c[ci], 0, 0, 0);
        }
        __builtin_amdgcn_s_setprio(0);
    }

    // prefetch V stage 0 (coalesced) -> latency hides under softmax
    bf16x8 vr0, vr1, vr2, vr3;
    {
        const bf16x8* g = (const bf16x8*)(vhb + (size_t)key * DEPTH + hf * 32);
        vr0 = g[0]; vr1 = g[1]; vr2 = g[2]; vr3 = g[3];
    }

    // ---- softmax on C-frags: row = 4*g4+reg, col = tile*16+li ----
    float mx[4], sm[4], inv[4];
    #pragma unroll
    for (int r = 0; r < 4; ++r) {
        float m_ = c[0][r];
        #pragma unroll
        for (int i = 1; i < 8; ++i) m_ = fmaxf(m_, c[i][r]);
        #pragma unroll
        for (int off = 1; off < 16; off <<= 1) m_ = fmaxf(m_, __shfl_xor(m_, off));
        mx[r] = m_;
    }
    if (li == 0) {
        #pragma unroll
        for (int r = 0; r < 4; ++r) redmax[(4 * g4 + r) * 8 + wid] = mx[r];
    }
    __syncthreads();
    #pragma unroll
    for (int r = 0; r < 4; ++r) {
        float m_ = redmax[(4 * g4 + r) * 8];
        #pragma unroll
        for (int w2 = 1; w2 < 8; ++w2) m_ = fmaxf(m_, redmax[(4 * g4 + r) * 8 + w2]);
        mx[r] = m_;
        sm[r] = 0.f;
    }
    #pragma unroll
    for (int i = 0; i < 8; ++i) {
        #pragma unroll
        for (int r = 0; r < 4; ++r) {
            const float e = __expf(c[i][r] - mx[r]);
            c[i][r] = e;
            sm[r] += e;
        }
    }
    #pragma unroll
    for (int r = 0; r < 4; ++r) {
        float s_ = sm[r];
        #pragma unroll
        for (int off = 1; off < 16; off <<= 1) s_ += __shfl_xor(s_, off);
        sm[r] = s_;
    }
    if (li == 0) {
        #pragma unroll
        for (int r = 0; r < 4; ++r) redsum[(4 * g4 + r) * 8 + wid] = sm[r];
    }
    __syncthreads();
    #pragma unroll
    for (int r = 0; r < 4; ++r) {
        float s_ = 0.f;
        #pragma unroll
        for (int w2 = 0; w2 < 8; ++w2) s_ += redsum[(4 * g4 + r) * 8 + w2];
        inv[r] = 1.f / s_;
    }
    // write P (bf16) rows 0-7 to pf
    if (l < 32) {
        #pragma unroll
        for (int i = 0; i < 8; ++i) {
            const int colbase = (16 * (i >> 1) + wid + 8 * (i & 1)) * 16 + li;
            #pragma unroll
            for (int r = 0; r < 4; ++r)
                pf[(4 * g4 + r) * 1032 + colbase] = f2bf(c[i][r] * inv[r]);
        }
    }
    __syncthreads();

    // ---- PV: 4 stages of 256 k, double-buffered; coalesced V loads + LDS transpose ----
    f32x4 cp = {0.f, 0.f, 0.f, 0.f};
    const int dt = wid >> 1, par = wid & 1;
    ushort* VT = kvbuf;                                  // [64][264]
    #pragma unroll
    for (int s = 0; s < 4; ++s) {
        if (s) __syncthreads();                          // prev stage MFMAs done
        {
            #pragma unroll
            for (int i = 0; i < 8; ++i) {
                VT[(hf * 32 + i     ) * 264 + key] = (ushort)vr0[i];
                VT[(hf * 32 + 8 + i ) * 264 + key] = (ushort)vr1[i];
                VT[(hf * 32 + 16 + i) * 264 + key] = (ushort)vr2[i];
                VT[(hf * 32 + 24 + i) * 264 + key] = (ushort)vr3[i];
            }
        }
        if (s < 3) {                                     // issue next stage loads now
            const bf16x8* g = (const bf16x8*)(vhb + (size_t)((s + 1) * 256 + key) * DEPTH + hf * 32);
            vr0 = g[0]; vr1 = g[1]; vr2 = g[2]; vr3 = g[3];
        }
        __syncthreads();
        __builtin_amdgcn_s_setprio(1);
        #pragma unroll
        for (int c2 = 0; c2 < 4; ++c2) {
            const int cc = par + 2 * c2;
            const bf16x8 ap = *(const bf16x8*)&pf[li * 1032 + s * 256 + cc * 32 + g4 * 8];
            const bf16x8 bv = *(const bf16x8*)&VT[(dt * 16 + li) * 264 + cc * 32 + g4 * 8];
            cp = __builtin_amdgcn_mfma_f32_16x16x32_bf16(ap, bv, cp, 0, 0, 0);
        }
        __builtin_amdgcn_s_setprio(0);
    }
    __syncthreads();

    // ---- reduce parity pairs -> ohT[64][12] ----
    float* part_f = (float*)kvbuf;                       // [8][256]
    float* ohT_f  = ((float*)kvbuf) + 2048;              // [64][12]
    #pragma unroll
    for (int r = 0; r < 4; ++r) part_f[wid * 256 + r * 64 + l] = cp[r];
    __syncthreads();
    {
        const int qq = t >> 6, dd = t & 63;
        const int ls = (qq >> 2) * 16 + (dd & 15), rr = qq & 3, w0 = (dd >> 4) * 2;
        ohT_f[dd * 12 + qq] = part_f[w0 * 256 + rr * 64 + ls] + part_f[(w0 + 1) * 256 + rr * 64 + ls];
    }
    __syncthreads();

    // ---- out rows = ohT @ Wr + bc  (all loads issued & consumed BEFORE the store burst) ----
    for (int j = t; j < DM; j += 512) {
        float a[QBLK];
        const float bj = bc[j];
        #pragma unroll
        for (int r = 0; r < QBLK; ++r) a[r] = bj;
        const float* wc = Wr + j;
        #pragma unroll 16
        for (int d2 = 0; d2 < DEPTH; ++d2) {
            const float wv = wc[(size_t)d2 * DM];
            const float4 o0 = *(const float4*)&ohT_f[d2 * 12];
            const float4 o1 = *(const float4*)&ohT_f[d2 * 12 + 4];
            a[0] = fmaf(o0.x, wv, a[0]); a[1] = fmaf(o0.y, wv, a[1]);
            a[2] = fmaf(o0.z, wv, a[2]); a[3] = fmaf(o0.w, wv, a[3]);
            a[4] = fmaf(o1.x, wv, a[4]); a[5] = fmaf(o1.y, wv, a[5]);
            a[6] = fmaf(o1.z, wv, a[6]); a[7] = fmaf(o1.w, wv, a[7]);
        }
        float* ob = out + ((size_t)b * SS + q0) * DM + j;
        #pragma unroll
        for (int r = 0; r < QBLK; ++r)
            __builtin_nontemporal_store(a[r], ob + (size_t)r * DM);
    }

    // ---- 12-head weight burst LAST: no dependent wait follows; next resident
    //      block computes while these drain ----
    {
        const int qq = t >> 6, c0 = t & 63;
        const ushort* prow = &pf[qq * 1032];
        float* abase = attn + ((size_t)(b * HH) * SS + (q0 + qq)) * SS;
        #pragma unroll
        for (int i = 0; i < 4; ++i) {
            const int col = i * 256 + c0 * 4;
            vfloat4 v4;
            v4.x = __uint_as_float((uint)prow[col + 0] << 16);
            v4.y = __uint_as_float((uint)prow[col + 1] << 16);
            v4.z = __uint_as_float((uint)prow[col + 2] << 16);
            v4.w = __uint_as_float((uint)prow[col + 3] << 16);
            #pragma unroll
            for (int h = 0; h < HH; ++h)
                __builtin_nontemporal_store(v4, (vfloat4*)(abase + (size_t)h * SS * SS + col));
        }
    }
}

extern "C" void kernel_launch(void* const* d_in, const int* in_sizes, int n_in,
                              void* d_out, int out_size, void* d_ws, size_t ws_size,
                              hipStream_t stream) {
    const float* q  = (const float*)d_in[0];
    const float* k  = (const float*)d_in[1];
    const float* v  = (const float*)d_in[2];
    const float* Wq = (const float*)d_in[3];
    const float* bq = (const float*)d_in[4];
    const float* Wk = (const float*)d_in[5];
    const float* bk = (const float*)d_in[6];
    const float* Wv = (const float*)d_in[7];
    const float* bv = (const float*)d_in[8];
    const float* Wc = (const float*)d_in[9];
    const float* bc = (const float*)d_in[10];

    float* out  = (float*)d_out;                              // [B,S,DM]
    float* attn = out + (size_t)BB * SS * DM;                 // [B,H,S,S]

    float* ws = (float*)d_ws;
    const size_t NPROJ = (size_t)NROWS * DEPTH;               // 262144
    float* qh   = ws;                                         // f32
    ushort* khu = (ushort*)(ws + NPROJ);                      // bf16
    ushort* vhu = (ushort*)(ws + NPROJ + NPROJ / 2);          // bf16
    float* Wr   = ws + 2 * NPROJ;                             // 64*768 f32

    wcred_kernel<<<(DEPTH * DM + 255) / 256, 256, 0, stream>>>(Wc, Wr);
    proj_kernel<<<3 * (NROWS / PROWS), 256, 0, stream>>>(q, k, v, Wq, bq, Wk, bk, Wv, bv, qh, khu, vhu);
    attn_core<<<BB * (SS / QBLK), 512, 0, stream>>>(qh, khu, vhu, Wr, bc, out, attn);
}